// Round 3
// baseline (559.749 us; speedup 1.0000x reference)
//
#include <hip/hip_runtime.h>

// Fused 3-layer LSTM + dense head, layer-pipelined wave specialization.
// B=2048, T=256, F=64, H=[64,32,16], OUT=1. fp32 in/out.
//
// bf16 3-term split MFMA (ah*wh + al*wh + ah*wl) for ~2^-16 precision.
// Block = 512 threads = 8 waves, grid = 256 (1 block/CU, BT=8 batches).
//   waves 0-3 : layer0 (h*U0 only) at step t     waves 4-5 : layer1 at t-1
//   wave  6   : layer2 at t-2                    wave  7   : z_x producer
//
// Round-8 change (resubmitted round 9 after infra failure): the x*W0+b0 part
// of layer0 has NO recurrence dependency. Wave 7 batch-computes z_x for 2
// timesteps at a time (M=2t*8b=16 rows, full MFMA row utilization -> 48
// MFMA/step vs the 96/step the L0 waves paid at 8/16-row occupancy),
// double-buffered in LDS one chunk ahead. L0 waves drop the x half (24
// MFMA/wave-step instead of 48) and init accumulators from z_x (which also
// absorbs the bias splat). Per-SIMD MFMA: 84/84/72/48 -> 60/60/48/72.
// W0 is pre-converted once to bf16 hi/lo fragments in LDS (64KB). x raw
// loads prefetched 2 chunks (~4 steps) ahead; producer never stalls on HBM.

typedef __attribute__((ext_vector_type(8))) short s8v;   // 8 x bf16
typedef __attribute__((ext_vector_type(4))) float f4v;   // 4 x f32
typedef unsigned short ushort_t;

#define T_STEPS 256
#define BT 8

// h-staging SMEM layout (units: shorts). chunk = [kgrp][row 0..15][j 0..7] = 512 shorts.
#define H0H 0       // [par][2 chunks], parity stride 1024
#define H0L 2048
#define H1H 4096    // [par][1 chunk],  parity stride 512
#define H1L 5120
#define H2H 6144    // [par][1 chunk],  parity stride 512 (k 16..31 = zero pad)
#define H2L 7168
#define SM_SHORTS 8192

#define PIN(v) asm volatile("" : "+v"(v))
#define BAR()  asm volatile("s_waitcnt lgkmcnt(0)\n\ts_barrier" ::: "memory")

__device__ __forceinline__ unsigned short f2bf(float f) {      // RTNE (weights, one-time)
    unsigned u = __float_as_uint(f);
    u += 0x7fff + ((u >> 16) & 1);
    return (unsigned short)(u >> 16);
}
__device__ __forceinline__ float bf2f(unsigned short s) {
    return __uint_as_float(((unsigned)s) << 16);
}
// cheap truncation split: hi = top 16 bits, lo = trunc(v - hi). Error <= 2^-16*|v|.
__device__ __forceinline__ void tsplit(float v, unsigned short& hi, unsigned short& lo) {
    unsigned u = __float_as_uint(v);
    hi = (unsigned short)(u >> 16);
    float r = v - __uint_as_float(u & 0xffff0000u);   // exact
    lo = (unsigned short)(__float_as_uint(r) >> 16);
}
__device__ __forceinline__ float sigmoid_f(float x) {
    return __builtin_amdgcn_rcpf(1.0f + __expf(-x));
}
__device__ __forceinline__ float tanh_f(float x) {
    return 1.0f - 2.0f * __builtin_amdgcn_rcpf(__expf(2.0f * x) + 1.0f);
}

// combined [W;U] weight element, zero-padded past KH rows
__device__ __forceinline__ float wval(const float* W, const float* U,
                                      int inDim, int KH, int fourH, int k, int n) {
    if (k < inDim) return W[k * fourH + n];
    if (k < KH)    return U[(k - inDim) * fourH + n];
    return 0.0f;
}
__device__ __forceinline__ void load_bfrag(const float* W, const float* U,
                                           int inDim, int KH, int fourH,
                                           int k0, int n, s8v& hi, s8v& lo) {
#pragma unroll
    for (int j = 0; j < 8; ++j) {
        float w = wval(W, U, inDim, KH, fourH, k0 + j, n);
        unsigned short h = f2bf(w);
        unsigned short l = f2bf(w - bf2f(h));
        hi[j] = (short)h;
        lo[j] = (short)l;
    }
}

// Gate math on 2 rows/lane after full-wave redistribution:
//   low lanes (fr<2)  : own regs {0,1}       -> rows fr*4 + {0,1}
//   high lanes (fr>=2): partner regs {2,3}   -> rows (fr-2)*4 + {2,3}
__device__ __forceinline__ void gates2(const f4v* acc, bool low, float* c, float* hn) {
#pragma unroll
    for (int j = 0; j < 2; ++j) {
        float si = __shfl_xor(acc[0][j + 2], 32);
        float sf = __shfl_xor(acc[1][j + 2], 32);
        float sg = __shfl_xor(acc[2][j + 2], 32);
        float so = __shfl_xor(acc[3][j + 2], 32);
        float zi = low ? acc[0][j] : si;
        float zf = low ? acc[1][j] : sf;
        float zg = low ? acc[2][j] : sg;
        float zo = low ? acc[3][j] : so;
        float ig = sigmoid_f(zi);
        float fg = sigmoid_f(zf);
        float gg = tanh_f(zg);
        float og = sigmoid_f(zo);
        c[j] = fmaf(fg, c[j], ig * gg);
        hn[j] = og * tanh_f(c[j]);
    }
}

// Produce z_x for 8 column-groups [CG0, CG0+8) of one 2-timestep chunk.
// A-frags axh/axl: lane(fr,fc) holds x[b=fc&7][t=chunk*2+(fc>>3)][k=kc*32+fr*8+j].
// C rows map row=fr*4+r -> t_local=fr>>1, b=(fr&1)*4+r.
template<int CG0>
__device__ __forceinline__ void produce8(const s8v* axh, const s8v* axl,
                                         const float* bw, int pcpar,
                                         int lane, int fr, int fc,
                                         ushort_t* w0s, float* zx)
{
    const int woff = (pcpar << 12) + ((fr >> 1) << 11) + ((fr & 1) << 2);
#pragma unroll
    for (int i = 0; i < 8; ++i) {
        const int cg = CG0 + i;
        const int col = cg * 16 + fc;
        const float bv = bw[cg];
        f4v acc = (f4v){bv, bv, bv, bv};
#pragma unroll
        for (int kc = 0; kc < 2; ++kc) {
            const int fb = ((cg * 2 + kc) << 9) + lane * 8;
            s8v bh = *(const s8v*)&w0s[fb];
            s8v bl = *(const s8v*)&w0s[16384 + fb];
            acc = __builtin_amdgcn_mfma_f32_16x16x32_bf16(axh[kc], bh, acc, 0, 0, 0);
            acc = __builtin_amdgcn_mfma_f32_16x16x32_bf16(axl[kc], bh, acc, 0, 0, 0);
            acc = __builtin_amdgcn_mfma_f32_16x16x32_bf16(axh[kc], bl, acc, 0, 0, 0);
        }
        *(f4v*)&zx[woff + col * 8] = acc;
    }
}

__global__ __attribute__((amdgpu_flat_work_group_size(512, 512),
                          amdgpu_waves_per_eu(2, 2)))
void lstm_pipe(const float* __restrict__ x,
               const float* __restrict__ W0, const float* __restrict__ U0, const float* __restrict__ b0,
               const float* __restrict__ W1, const float* __restrict__ U1, const float* __restrict__ b1,
               const float* __restrict__ W2, const float* __restrict__ U2, const float* __restrict__ b2,
               const float* __restrict__ Wd, const float* __restrict__ bd,
               float* __restrict__ out)
{
    const int tid  = threadIdx.x;
    const int lane = tid & 63;
    const int wv   = tid >> 6;          // 0..7
    const int fr   = lane >> 4;         // k-group / C row-group
    const int fc   = lane & 15;         // frag column
    const int bbase = blockIdx.x * BT;

    __shared__ __align__(16) ushort_t SMEM[SM_SHORTS];          // h staging, 16KB
    __shared__ __align__(16) float    ZX[8192];                 // z_x dbuf [par][2t][256col][8b], 32KB
    __shared__ __align__(16) ushort_t W0S[32768];               // W0 bf16 hi/lo frags, 64KB
    __shared__ __align__(16) float h2last[BT][16];

    // zero h staging (K-pad regions must stay zero; h init = 0)
    {
        unsigned* p32 = (unsigned*)SMEM;
        for (int i = tid; i < SM_SHORTS / 2; i += 512) p32[i] = 0u;
    }
    // stage W0 -> bf16 hi/lo fragments in LDS (one-time).
    // frag pos: [cg][kc] frag of 512 shorts; short idx = ((cg*2+kc)*64 + lane)*8 + j
    // holds W0[k = kc*32 + (lane>>4)*8 + j][n = cg*16 + (lane&15)].
    for (int it = tid; it < 16384; it += 512) {
        const int n = it & 255;
        const int k = it >> 8;
        const float w = W0[it];
        const int kc = k >> 5, kfr = (k >> 3) & 3, j = k & 7;
        const int cg = n >> 4, nfc = n & 15;
        const int pos = ((cg * 2 + kc) * 64 + (kfr * 16 + nfc)) * 8 + j;
        unsigned short h = f2bf(w);
        W0S[pos] = h;
        W0S[16384 + pos] = f2bf(w - bf2f(h));
    }
    __syncthreads();                                    // barrier #1

    const ushort_t* rb = SMEM + lane * 8;               // frag read base (all roles)
    const bool low = (lane < 32);
    const int rowb = (fr & 1) * 4 + ((fr >> 1) << 1);   // this lane's h row base (0,4,2,6)

    if (wv < 4) {
        // =================== layer0 role (waves 0..3): h*U0 only ===================
        s8v Bh[4][2], Bl[4][2];                         // [gate][kc]  (K = 64 = U0)
#pragma unroll
        for (int g = 0; g < 4; ++g) {
            int n = g * 64 + wv * 16 + fc;
#pragma unroll
            for (int kc = 0; kc < 2; ++kc)
                load_bfrag(U0, U0, 64, 64, 256, kc * 32 + fr * 8, n, Bh[g][kc], Bl[g][kc]);
        }
#pragma unroll
        for (int g = 0; g < 4; ++g)
#pragma unroll
            for (int kc = 0; kc < 2; ++kc) { PIN(Bh[g][kc]); PIN(Bl[g][kc]); }
        float c0[2] = {0.f, 0.f};
        const int hq  = wv >> 1;                        // h0 chunk this wave writes
        const int k   = (wv & 1) * 16 + fc;             // k within chunk
        const int ibw = (k >> 3) * 128 + (k & 7);       // lane-dep write offset
        const int zb  = (wv * 16 + fc) * 8 + ((fr & 1) << 2);   // z_x read base (floats)
        __syncthreads();                                // barrier #2
        for (int s = 0; s < T_STEPS + 2; ++s) {
            if (s < T_STEPS) {
                const ushort_t* r = rb + ((s & 1) << 10);   // H0 parity*1024 shorts
                s8v ah0 = *(const s8v*)&r[H0H +   0];
                s8v al0 = *(const s8v*)&r[H0L +   0];
                s8v ah1 = *(const s8v*)&r[H0H + 512];
                s8v al1 = *(const s8v*)&r[H0L + 512];
                // acc init = z_x(t) (bias already folded in by producer)
                const float* zr = ZX + ((((s >> 1) & 1) << 12) + ((s & 1) << 11) + zb);
                f4v acc[4];
#pragma unroll
                for (int g = 0; g < 4; ++g) acc[g] = *(const f4v*)&zr[g * 512];
                // same-acc distance 4: latency hidden by the 4 independent g chains
#pragma unroll
                for (int g = 0; g < 4; ++g)
                    acc[g] = __builtin_amdgcn_mfma_f32_16x16x32_bf16(ah0, Bh[g][0], acc[g], 0, 0, 0);
#pragma unroll
                for (int g = 0; g < 4; ++g)
                    acc[g] = __builtin_amdgcn_mfma_f32_16x16x32_bf16(al0, Bh[g][0], acc[g], 0, 0, 0);
#pragma unroll
                for (int g = 0; g < 4; ++g)
                    acc[g] = __builtin_amdgcn_mfma_f32_16x16x32_bf16(ah0, Bl[g][0], acc[g], 0, 0, 0);
#pragma unroll
                for (int g = 0; g < 4; ++g)
                    acc[g] = __builtin_amdgcn_mfma_f32_16x16x32_bf16(ah1, Bh[g][1], acc[g], 0, 0, 0);
#pragma unroll
                for (int g = 0; g < 4; ++g)
                    acc[g] = __builtin_amdgcn_mfma_f32_16x16x32_bf16(al1, Bh[g][1], acc[g], 0, 0, 0);
#pragma unroll
                for (int g = 0; g < 4; ++g)
                    acc[g] = __builtin_amdgcn_mfma_f32_16x16x32_bf16(ah1, Bl[g][1], acc[g], 0, 0, 0);
                float hn[2];
                gates2(acc, low, c0, hn);
                {
                    ushort_t* w = SMEM + (((s & 1) ^ 1) << 10) + hq * 512 + ibw;
#pragma unroll
                    for (int j = 0; j < 2; ++j) {
                        unsigned short hh_, ll_;
                        tsplit(hn[j], hh_, ll_);
                        w[H0H + (rowb + j) * 8] = hh_;
                        w[H0L + (rowb + j) * 8] = ll_;
                    }
                }
            }
            BAR();
        }
    } else if (wv < 6) {
        // =================== layer1 role (waves 4,5) ===================
        s8v Bh[4][3], Bl[4][3];
        float bias[4];
#pragma unroll
        for (int g = 0; g < 4; ++g) {
            int n = g * 32 + (wv & 1) * 16 + fc;
            bias[g] = b1[n];
#pragma unroll
            for (int kc = 0; kc < 3; ++kc)
                load_bfrag(W1, U1, 64, 96, 128, kc * 32 + fr * 8, n, Bh[g][kc], Bl[g][kc]);
        }
#pragma unroll
        for (int g = 0; g < 4; ++g) {
            PIN(bias[g]);
#pragma unroll
            for (int kc = 0; kc < 3; ++kc) { PIN(Bh[g][kc]); PIN(Bl[g][kc]); }
        }
        float c1[2] = {0.f, 0.f};
        const int k   = (wv & 1) * 16 + fc;
        const int ibw = (k >> 3) * 128 + (k & 7);
        __syncthreads();                                // barrier #2
        for (int s = 0; s < T_STEPS + 2; ++s) {
            if (s >= 1 && s <= T_STEPS) {
                const int p = s & 1;
                const ushort_t* r  = rb + (p << 10);    // H0 parity stride 1024
                const ushort_t* r1 = rb + (p << 9);     // H1 parity stride 512
                s8v ah[3], al[3];
                ah[0] = *(const s8v*)&r[H0H +   0];
                al[0] = *(const s8v*)&r[H0L +   0];
                ah[1] = *(const s8v*)&r[H0H + 512];
                al[1] = *(const s8v*)&r[H0L + 512];
                ah[2] = *(const s8v*)&r1[H1H];
                al[2] = *(const s8v*)&r1[H1L];
                f4v acc[4];
#pragma unroll
                for (int g = 0; g < 4; ++g) acc[g] = (f4v){bias[g], bias[g], bias[g], bias[g]};
#pragma unroll
                for (int kc = 0; kc < 3; ++kc) {
#pragma unroll
                    for (int g = 0; g < 4; ++g)
                        acc[g] = __builtin_amdgcn_mfma_f32_16x16x32_bf16(ah[kc], Bh[g][kc], acc[g], 0, 0, 0);
#pragma unroll
                    for (int g = 0; g < 4; ++g)
                        acc[g] = __builtin_amdgcn_mfma_f32_16x16x32_bf16(al[kc], Bh[g][kc], acc[g], 0, 0, 0);
#pragma unroll
                    for (int g = 0; g < 4; ++g)
                        acc[g] = __builtin_amdgcn_mfma_f32_16x16x32_bf16(ah[kc], Bl[g][kc], acc[g], 0, 0, 0);
                }
                float hn[2];
                gates2(acc, low, c1, hn);
                {
                    ushort_t* w = SMEM + ((p ^ 1) << 9) + ibw;
#pragma unroll
                    for (int j = 0; j < 2; ++j) {
                        unsigned short hh_, ll_;
                        tsplit(hn[j], hh_, ll_);
                        w[H1H + (rowb + j) * 8] = hh_;
                        w[H1L + (rowb + j) * 8] = ll_;
                    }
                }
            }
            BAR();
        }
    } else if (wv == 6) {
        // =================== layer2 role (wave 6) ===================
        s8v Bh[4][2], Bl[4][2];
        float bias[4];
#pragma unroll
        for (int g = 0; g < 4; ++g) {
            int n = g * 16 + fc;
            bias[g] = b2[n];
#pragma unroll
            for (int kc = 0; kc < 2; ++kc)
                load_bfrag(W2, U2, 32, 48, 64, kc * 32 + fr * 8, n, Bh[g][kc], Bl[g][kc]);
        }
#pragma unroll
        for (int g = 0; g < 4; ++g) {
            PIN(bias[g]);
#pragma unroll
            for (int kc = 0; kc < 2; ++kc) { PIN(Bh[g][kc]); PIN(Bl[g][kc]); }
        }
        float c2[2] = {0.f, 0.f};
        const int ibw = (fc >> 3) * 128 + (fc & 7);     // k = fc (0..15)
        __syncthreads();                                // barrier #2
        for (int s = 0; s < T_STEPS + 2; ++s) {
            if (s >= 2) {
                const int p = s & 1;
                const ushort_t* r1 = rb + (p << 9);     // H1,H2 parity stride 512
                s8v ah[2], al[2];
                ah[0] = *(const s8v*)&r1[H1H];
                al[0] = *(const s8v*)&r1[H1L];
                ah[1] = *(const s8v*)&r1[H2H];
                al[1] = *(const s8v*)&r1[H2L];
                f4v acc[4];
#pragma unroll
                for (int g = 0; g < 4; ++g) acc[g] = (f4v){bias[g], bias[g], bias[g], bias[g]};
#pragma unroll
                for (int kc = 0; kc < 2; ++kc) {
#pragma unroll
                    for (int g = 0; g < 4; ++g)
                        acc[g] = __builtin_amdgcn_mfma_f32_16x16x32_bf16(ah[kc], Bh[g][kc], acc[g], 0, 0, 0);
#pragma unroll
                    for (int g = 0; g < 4; ++g)
                        acc[g] = __builtin_amdgcn_mfma_f32_16x16x32_bf16(al[kc], Bh[g][kc], acc[g], 0, 0, 0);
#pragma unroll
                    for (int g = 0; g < 4; ++g)
                        acc[g] = __builtin_amdgcn_mfma_f32_16x16x32_bf16(ah[kc], Bl[g][kc], acc[g], 0, 0, 0);
                }
                float hn[2];
                gates2(acc, low, c2, hn);
                {
                    ushort_t* w = SMEM + ((p ^ 1) << 9) + ibw;
#pragma unroll
                    for (int j = 0; j < 2; ++j) {
                        unsigned short hh_, ll_;
                        tsplit(hn[j], hh_, ll_);
                        w[H2H + (rowb + j) * 8] = hh_;
                        w[H2L + (rowb + j) * 8] = ll_;
                    }
                    if (s == T_STEPS + 1) {             // t2 = 255: final h2
#pragma unroll
                        for (int j = 0; j < 2; ++j) h2last[rowb + j][fc] = hn[j];
                    }
                }
            }
            BAR();
        }
    } else {
        // =================== z_x producer role (wave 7) ===================
        // chunk c covers t = 2c, 2c+1 (128 chunks). During steps {2c, 2c+1}
        // produce chunk c+1 into parity (c+1)&1; consumers read chunk c.
        float bw[16];
#pragma unroll
        for (int cg = 0; cg < 16; ++cg) bw[cg] = b0[cg * 16 + fc];
        const int tl = fc >> 3;                         // A-row t_local
        const float* xlane = x + ((size_t)(bbase + (fc & 7)) * T_STEPS) * 64 + fr * 8;

        auto xload = [&](int cc, float4* rx) {
            const float* p = xlane + (size_t)(cc * 2 + tl) * 64;
            rx[0] = *(const float4*)(p);
            rx[1] = *(const float4*)(p + 4);
            rx[2] = *(const float4*)(p + 32);
            rx[3] = *(const float4*)(p + 36);
        };
        auto dotsplit = [&](const float4* rx, s8v* axh, s8v* axl) {
#pragma unroll
            for (int kc = 0; kc < 2; ++kc) {
                float vv[8] = {rx[kc*2].x, rx[kc*2].y, rx[kc*2].z, rx[kc*2].w,
                               rx[kc*2+1].x, rx[kc*2+1].y, rx[kc*2+1].z, rx[kc*2+1].w};
#pragma unroll
                for (int j = 0; j < 8; ++j) {
                    unsigned short h_, l_;
                    tsplit(vv[j], h_, l_);
                    axh[kc][j] = (short)h_;
                    axl[kc][j] = (short)l_;
                }
            }
        };

        s8v axh[2], axl[2];
        float4 rxA[4], rxB[4], rt[4];
        // prologue: produce chunk 0 (parity 0); prep frags for chunk 1;
        // prefetch raw x of chunk 2 into rxA. (W0S ready after barrier #1.)
        xload(0, rt);
        dotsplit(rt, axh, axl);
        produce8<0>(axh, axl, bw, 0, lane, fr, fc, W0S, ZX);
        produce8<8>(axh, axl, bw, 0, lane, fr, fc, W0S, ZX);
        xload(1, rt);
        dotsplit(rt, axh, axl);
        xload(2, rxA);
        __syncthreads();                                // barrier #2
        for (int s = 0; s < T_STEPS + 2; ++s) {
            if (s < 2 * 127) {                          // last produced chunk = 127
                const int c = s >> 1;
                const int pcpar = (c + 1) & 1;
                if ((s & 1) == 0) {
                    produce8<0>(axh, axl, bw, pcpar, lane, fr, fc, W0S, ZX);
                } else {
                    produce8<8>(axh, axl, bw, pcpar, lane, fr, fc, W0S, ZX);
                    // frags for chunk c+2 (raw loaded 2 steps ago); then issue
                    // raw loads for chunk c+3 into the other buffer.
                    if (c + 2 <= 127) {
                        if ((c & 1) == 0) dotsplit(rxA, axh, axl);
                        else              dotsplit(rxB, axh, axl);
                    }
                    if (c + 3 <= 127) {
                        if ((c & 1) == 0) xload(c + 3, rxB);
                        else              xload(c + 3, rxA);
                    }
                }
            }
            BAR();
        }
    }

    __syncthreads();
    // =================== dense head ===================
    if (tid < BT) {
        float acc = bd[0];
#pragma unroll
        for (int j = 0; j < 16; ++j) acc += h2last[tid][j] * Wd[j];
        out[bbase + tid] = acc;
    }
}

extern "C" void kernel_launch(void* const* d_in, const int* in_sizes, int n_in,
                              void* d_out, int out_size, void* d_ws, size_t ws_size,
                              hipStream_t stream) {
    (void)in_sizes; (void)n_in; (void)d_ws; (void)ws_size; (void)out_size;
    const float* x  = (const float*)d_in[0];
    const float* W0 = (const float*)d_in[1];
    const float* U0 = (const float*)d_in[2];
    const float* b0 = (const float*)d_in[3];
    const float* W1 = (const float*)d_in[4];
    const float* U1 = (const float*)d_in[5];
    const float* b1 = (const float*)d_in[6];
    const float* W2 = (const float*)d_in[7];
    const float* U2 = (const float*)d_in[8];
    const float* b2 = (const float*)d_in[9];
    const float* Wd = (const float*)d_in[10];
    const float* bd = (const float*)d_in[11];
    float* out = (float*)d_out;

    dim3 grid(2048 / BT);   // 256 blocks, 1 per CU
    dim3 block(512);        // 8 waves, 2 per SIMD
    hipLaunchKernelGGL(lstm_pipe, grid, block, 0, stream,
                       x, W0, U0, b0, W1, U1, b1, W2, U2, b2, Wd, bd, out);
}

// Round 6
// 541.651 us; speedup vs baseline: 1.0334x; 1.0334x over previous
//
#include <hip/hip_runtime.h>

// Fused 3-layer LSTM + dense head, layer-pipelined wave specialization.
// B=2048, T=256, F=64, H=[64,32,16], OUT=1. fp32 in/out.
//
// bf16 3-term split MFMA (ah*wh + al*wh + ah*wl) for ~2^-16 precision.
// Block = 512 threads = 8 waves, grid = 256 (1 block/CU, BT=8 batches).
//   waves 0-3 : layer0 (h*U0 only) at step t     waves 4-5 : layer1 at t-1
//   wave  6   : layer2 at t-2                    wave  7   : z_x producer
//
// Round-10 fixes (R3 regressed 302->452us: producer's per-cg LDS reads were
// serial -- ds_read -> lgkmcnt(0) ~120cy -> 6 distance-1 MFMAs ~96cy, x8 cg
// = ~1800cy/step of exposed latency on wave 7). Resubmitted (3rd time) after
// repeated infra container failures; audit found no hang/OOB/deadlock path:
//  * produce8p: cg processed in pairs with ping-pong fragment registers;
//    next pair's 8 ds_read_b128 issue BEFORE current pair's 12 MFMAs (two
//    interleaved distance-2 acc chains) -> LDS latency hidden under MFMA.
//  * ZX padded: zoff(col)=col*8+(col>>1)*4 (16B-aligned), tl stride 2568,
//    par stride 5136 -> <=2-way LDS bank aliasing (free) on producer stores
//    and consumer acc-init reads (was 8-way at the old 32B lane stride).

typedef __attribute__((ext_vector_type(8))) short s8v;   // 8 x bf16
typedef __attribute__((ext_vector_type(4))) float f4v;   // 4 x f32
typedef unsigned short ushort_t;

#define T_STEPS 256
#define BT 8

// h-staging SMEM layout (units: shorts). chunk = [kgrp][row 0..15][j 0..7] = 512 shorts.
#define H0H 0       // [par][2 chunks], parity stride 1024
#define H0L 2048
#define H1H 4096    // [par][1 chunk],  parity stride 512
#define H1L 5120
#define H2H 6144    // [par][1 chunk],  parity stride 512 (k 16..31 = zero pad)
#define H2L 7168
#define SM_SHORTS 8192

// ZX: z_x double buffer, padded. float idx = par*5136 + tl*2568 + zoff(col) + (fr&1)*4
// zoff(col) = col*8 + (col>>1)*4  (col = gate-column 0..255, 8 floats = batch dim)
#define ZXBLK 2568
#define ZXPAR 5136
#define ZX_FLOATS 10272

#define PIN(v) asm volatile("" : "+v"(v))
#define BAR()  asm volatile("s_waitcnt lgkmcnt(0)\n\ts_barrier" ::: "memory")

__device__ __forceinline__ unsigned short f2bf(float f) {      // RTNE (weights, one-time)
    unsigned u = __float_as_uint(f);
    u += 0x7fff + ((u >> 16) & 1);
    return (unsigned short)(u >> 16);
}
__device__ __forceinline__ float bf2f(unsigned short s) {
    return __uint_as_float(((unsigned)s) << 16);
}
// cheap truncation split: hi = top 16 bits, lo = trunc(v - hi). Error <= 2^-16*|v|.
__device__ __forceinline__ void tsplit(float v, unsigned short& hi, unsigned short& lo) {
    unsigned u = __float_as_uint(v);
    hi = (unsigned short)(u >> 16);
    float r = v - __uint_as_float(u & 0xffff0000u);   // exact
    lo = (unsigned short)(__float_as_uint(r) >> 16);
}
__device__ __forceinline__ float sigmoid_f(float x) {
    return __builtin_amdgcn_rcpf(1.0f + __expf(-x));
}
__device__ __forceinline__ float tanh_f(float x) {
    return 1.0f - 2.0f * __builtin_amdgcn_rcpf(__expf(2.0f * x) + 1.0f);
}

// combined [W;U] weight element, zero-padded past KH rows
__device__ __forceinline__ float wval(const float* W, const float* U,
                                      int inDim, int KH, int fourH, int k, int n) {
    if (k < inDim) return W[k * fourH + n];
    if (k < KH)    return U[(k - inDim) * fourH + n];
    return 0.0f;
}
__device__ __forceinline__ void load_bfrag(const float* W, const float* U,
                                           int inDim, int KH, int fourH,
                                           int k0, int n, s8v& hi, s8v& lo) {
#pragma unroll
    for (int j = 0; j < 8; ++j) {
        float w = wval(W, U, inDim, KH, fourH, k0 + j, n);
        unsigned short h = f2bf(w);
        unsigned short l = f2bf(w - bf2f(h));
        hi[j] = (short)h;
        lo[j] = (short)l;
    }
}

// Gate math on 2 rows/lane after full-wave redistribution:
//   low lanes (fr<2)  : own regs {0,1}       -> rows fr*4 + {0,1}
//   high lanes (fr>=2): partner regs {2,3}   -> rows (fr-2)*4 + {2,3}
__device__ __forceinline__ void gates2(const f4v* acc, bool low, float* c, float* hn) {
#pragma unroll
    for (int j = 0; j < 2; ++j) {
        float si = __shfl_xor(acc[0][j + 2], 32);
        float sf = __shfl_xor(acc[1][j + 2], 32);
        float sg = __shfl_xor(acc[2][j + 2], 32);
        float so = __shfl_xor(acc[3][j + 2], 32);
        float zi = low ? acc[0][j] : si;
        float zf = low ? acc[1][j] : sf;
        float zg = low ? acc[2][j] : sg;
        float zo = low ? acc[3][j] : so;
        float ig = sigmoid_f(zi);
        float fg = sigmoid_f(zf);
        float gg = tanh_f(zg);
        float og = sigmoid_f(zo);
        c[j] = fmaf(fg, c[j], ig * gg);
        hn[j] = og * tanh_f(c[j]);
    }
}

// Produce z_x for 8 column-groups [CG0, CG0+8) of one 2-timestep chunk.
// Software-pipelined: cg pairs, ping-pong W0S fragment regs; next pair's
// ds_reads issue before current pair's 12 MFMAs (2 interleaved acc chains).
// A-frags axh/axl: lane(fr,fc) holds x[b=fc&7][t=chunk*2+(fc>>3)][k=kc*32+fr*8+j].
// C rows map row=fr*4+r -> t_local=fr>>1, b=(fr&1)*4+r.
template<int CG0>
__device__ __forceinline__ void produce8p(const s8v* axh, const s8v* axl,
                                          const float* bw, int pcpar,
                                          int lane, int fr, int fc,
                                          const ushort_t* w0s, float* zx)
{
    const int woff = pcpar * ZXPAR + (fr >> 1) * ZXBLK + ((fr & 1) << 2);
    const int cb = fc * 8 + ((fc >> 1) << 2);           // zoff contribution of fc
    s8v bh[2][4], bl[2][4];                             // [pingpong][cgl*2+kc]
    // preload pair 0
#pragma unroll
    for (int q = 0; q < 4; ++q) {
        const int fb = (((CG0 + (q >> 1)) * 2 + (q & 1)) << 9) + lane * 8;
        bh[0][q] = *(const s8v*)&w0s[fb];
        bl[0][q] = *(const s8v*)&w0s[16384 + fb];
    }
#pragma unroll
    for (int ip = 0; ip < 4; ++ip) {
        const int cg0 = CG0 + ip * 2;
        if (ip < 3) {                                   // prefetch next pair
#pragma unroll
            for (int q = 0; q < 4; ++q) {
                const int fb = (((cg0 + 2 + (q >> 1)) * 2 + (q & 1)) << 9) + lane * 8;
                bh[(ip + 1) & 1][q] = *(const s8v*)&w0s[fb];
                bl[(ip + 1) & 1][q] = *(const s8v*)&w0s[16384 + fb];
            }
        }
        const int A = ip & 1;
        const float b0v = bw[cg0], b1v = bw[cg0 + 1];
        f4v a0 = (f4v){b0v, b0v, b0v, b0v};
        f4v a1 = (f4v){b1v, b1v, b1v, b1v};
#pragma unroll
        for (int kc = 0; kc < 2; ++kc) {
            a0 = __builtin_amdgcn_mfma_f32_16x16x32_bf16(axh[kc], bh[A][kc],     a0, 0, 0, 0);
            a1 = __builtin_amdgcn_mfma_f32_16x16x32_bf16(axh[kc], bh[A][2 + kc], a1, 0, 0, 0);
            a0 = __builtin_amdgcn_mfma_f32_16x16x32_bf16(axl[kc], bh[A][kc],     a0, 0, 0, 0);
            a1 = __builtin_amdgcn_mfma_f32_16x16x32_bf16(axl[kc], bh[A][2 + kc], a1, 0, 0, 0);
            a0 = __builtin_amdgcn_mfma_f32_16x16x32_bf16(axh[kc], bl[A][kc],     a0, 0, 0, 0);
            a1 = __builtin_amdgcn_mfma_f32_16x16x32_bf16(axh[kc], bl[A][2 + kc], a1, 0, 0, 0);
        }
        *(f4v*)&zx[woff + cg0 * 160 + cb] = a0;
        *(f4v*)&zx[woff + (cg0 + 1) * 160 + cb] = a1;
    }
}

__global__ __attribute__((amdgpu_flat_work_group_size(512, 512),
                          amdgpu_waves_per_eu(2, 2)))
void lstm_pipe(const float* __restrict__ x,
               const float* __restrict__ W0, const float* __restrict__ U0, const float* __restrict__ b0,
               const float* __restrict__ W1, const float* __restrict__ U1, const float* __restrict__ b1,
               const float* __restrict__ W2, const float* __restrict__ U2, const float* __restrict__ b2,
               const float* __restrict__ Wd, const float* __restrict__ bd,
               float* __restrict__ out)
{
    const int tid  = threadIdx.x;
    const int lane = tid & 63;
    const int wv   = tid >> 6;          // 0..7
    const int fr   = lane >> 4;         // k-group / C row-group
    const int fc   = lane & 15;         // frag column
    const int bbase = blockIdx.x * BT;

    __shared__ __align__(16) ushort_t SMEM[SM_SHORTS];          // h staging, 16KB
    __shared__ __align__(16) float    ZX[ZX_FLOATS];            // z_x dbuf, padded, ~40KB
    __shared__ __align__(16) ushort_t W0S[32768];               // W0 bf16 hi/lo frags, 64KB
    __shared__ __align__(16) float h2last[BT][16];

    // zero h staging (K-pad regions must stay zero; h init = 0)
    {
        unsigned* p32 = (unsigned*)SMEM;
        for (int i = tid; i < SM_SHORTS / 2; i += 512) p32[i] = 0u;
    }
    // stage W0 -> bf16 hi/lo fragments in LDS (one-time).
    // frag pos: [cg][kc] frag of 512 shorts; short idx = ((cg*2+kc)*64 + lane)*8 + j
    // holds W0[k = kc*32 + (lane>>4)*8 + j][n = cg*16 + (lane&15)].
    for (int it = tid; it < 16384; it += 512) {
        const int n = it & 255;
        const int k = it >> 8;
        const float w = W0[it];
        const int kc = k >> 5, kfr = (k >> 3) & 3, j = k & 7;
        const int cg = n >> 4, nfc = n & 15;
        const int pos = ((cg * 2 + kc) * 64 + (kfr * 16 + nfc)) * 8 + j;
        unsigned short h = f2bf(w);
        W0S[pos] = h;
        W0S[16384 + pos] = f2bf(w - bf2f(h));
    }
    __syncthreads();                                    // barrier #1

    const ushort_t* rb = SMEM + lane * 8;               // frag read base (all roles)
    const bool low = (lane < 32);
    const int rowb = (fr & 1) * 4 + ((fr >> 1) << 1);   // this lane's h row base (0,4,2,6)

    if (wv < 4) {
        // =================== layer0 role (waves 0..3): h*U0 only ===================
        s8v Bh[4][2], Bl[4][2];                         // [gate][kc]  (K = 64 = U0)
#pragma unroll
        for (int g = 0; g < 4; ++g) {
            int n = g * 64 + wv * 16 + fc;
#pragma unroll
            for (int kc = 0; kc < 2; ++kc)
                load_bfrag(U0, U0, 64, 64, 256, kc * 32 + fr * 8, n, Bh[g][kc], Bl[g][kc]);
        }
#pragma unroll
        for (int g = 0; g < 4; ++g)
#pragma unroll
            for (int kc = 0; kc < 2; ++kc) { PIN(Bh[g][kc]); PIN(Bl[g][kc]); }
        float c0[2] = {0.f, 0.f};
        const int hq  = wv >> 1;                        // h0 chunk this wave writes
        const int k   = (wv & 1) * 16 + fc;             // k within chunk
        const int ibw = (k >> 3) * 128 + (k & 7);       // lane-dep write offset
        const int Wc  = wv * 16 + fc;                   // z_x column (gate-local)
        const int zb  = Wc * 8 + ((Wc >> 1) << 2) + ((fr & 1) << 2);
        __syncthreads();                                // barrier #2
        for (int s = 0; s < T_STEPS + 2; ++s) {
            if (s < T_STEPS) {
                const ushort_t* r = rb + ((s & 1) << 10);   // H0 parity*1024 shorts
                s8v ah0 = *(const s8v*)&r[H0H +   0];
                s8v al0 = *(const s8v*)&r[H0L +   0];
                s8v ah1 = *(const s8v*)&r[H0H + 512];
                s8v al1 = *(const s8v*)&r[H0L + 512];
                // acc init = z_x(t) (bias already folded in by producer)
                const float* zr = ZX + (((s >> 1) & 1) * ZXPAR + (s & 1) * ZXBLK + zb);
                f4v acc[4];
#pragma unroll
                for (int g = 0; g < 4; ++g) acc[g] = *(const f4v*)&zr[g * 640];
                // same-acc distance 4: latency hidden by the 4 independent g chains
#pragma unroll
                for (int g = 0; g < 4; ++g)
                    acc[g] = __builtin_amdgcn_mfma_f32_16x16x32_bf16(ah0, Bh[g][0], acc[g], 0, 0, 0);
#pragma unroll
                for (int g = 0; g < 4; ++g)
                    acc[g] = __builtin_amdgcn_mfma_f32_16x16x32_bf16(al0, Bh[g][0], acc[g], 0, 0, 0);
#pragma unroll
                for (int g = 0; g < 4; ++g)
                    acc[g] = __builtin_amdgcn_mfma_f32_16x16x32_bf16(ah0, Bl[g][0], acc[g], 0, 0, 0);
#pragma unroll
                for (int g = 0; g < 4; ++g)
                    acc[g] = __builtin_amdgcn_mfma_f32_16x16x32_bf16(ah1, Bh[g][1], acc[g], 0, 0, 0);
#pragma unroll
                for (int g = 0; g < 4; ++g)
                    acc[g] = __builtin_amdgcn_mfma_f32_16x16x32_bf16(al1, Bh[g][1], acc[g], 0, 0, 0);
#pragma unroll
                for (int g = 0; g < 4; ++g)
                    acc[g] = __builtin_amdgcn_mfma_f32_16x16x32_bf16(ah1, Bl[g][1], acc[g], 0, 0, 0);
                float hn[2];
                gates2(acc, low, c0, hn);
                {
                    ushort_t* w = SMEM + (((s & 1) ^ 1) << 10) + hq * 512 + ibw;
#pragma unroll
                    for (int j = 0; j < 2; ++j) {
                        unsigned short hh_, ll_;
                        tsplit(hn[j], hh_, ll_);
                        w[H0H + (rowb + j) * 8] = hh_;
                        w[H0L + (rowb + j) * 8] = ll_;
                    }
                }
            }
            BAR();
        }
    } else if (wv < 6) {
        // =================== layer1 role (waves 4,5) ===================
        s8v Bh[4][3], Bl[4][3];
        float bias[4];
#pragma unroll
        for (int g = 0; g < 4; ++g) {
            int n = g * 32 + (wv & 1) * 16 + fc;
            bias[g] = b1[n];
#pragma unroll
            for (int kc = 0; kc < 3; ++kc)
                load_bfrag(W1, U1, 64, 96, 128, kc * 32 + fr * 8, n, Bh[g][kc], Bl[g][kc]);
        }
#pragma unroll
        for (int g = 0; g < 4; ++g) {
            PIN(bias[g]);
#pragma unroll
            for (int kc = 0; kc < 3; ++kc) { PIN(Bh[g][kc]); PIN(Bl[g][kc]); }
        }
        float c1[2] = {0.f, 0.f};
        const int k   = (wv & 1) * 16 + fc;
        const int ibw = (k >> 3) * 128 + (k & 7);
        __syncthreads();                                // barrier #2
        for (int s = 0; s < T_STEPS + 2; ++s) {
            if (s >= 1 && s <= T_STEPS) {
                const int p = s & 1;
                const ushort_t* r  = rb + (p << 10);    // H0 parity stride 1024
                const ushort_t* r1 = rb + (p << 9);     // H1 parity stride 512
                s8v ah[3], al[3];
                ah[0] = *(const s8v*)&r[H0H +   0];
                al[0] = *(const s8v*)&r[H0L +   0];
                ah[1] = *(const s8v*)&r[H0H + 512];
                al[1] = *(const s8v*)&r[H0L + 512];
                ah[2] = *(const s8v*)&r1[H1H];
                al[2] = *(const s8v*)&r1[H1L];
                f4v acc[4];
#pragma unroll
                for (int g = 0; g < 4; ++g) acc[g] = (f4v){bias[g], bias[g], bias[g], bias[g]};
#pragma unroll
                for (int kc = 0; kc < 3; ++kc) {
#pragma unroll
                    for (int g = 0; g < 4; ++g)
                        acc[g] = __builtin_amdgcn_mfma_f32_16x16x32_bf16(ah[kc], Bh[g][kc], acc[g], 0, 0, 0);
#pragma unroll
                    for (int g = 0; g < 4; ++g)
                        acc[g] = __builtin_amdgcn_mfma_f32_16x16x32_bf16(al[kc], Bh[g][kc], acc[g], 0, 0, 0);
#pragma unroll
                    for (int g = 0; g < 4; ++g)
                        acc[g] = __builtin_amdgcn_mfma_f32_16x16x32_bf16(ah[kc], Bl[g][kc], acc[g], 0, 0, 0);
                }
                float hn[2];
                gates2(acc, low, c1, hn);
                {
                    ushort_t* w = SMEM + ((p ^ 1) << 9) + ibw;
#pragma unroll
                    for (int j = 0; j < 2; ++j) {
                        unsigned short hh_, ll_;
                        tsplit(hn[j], hh_, ll_);
                        w[H1H + (rowb + j) * 8] = hh_;
                        w[H1L + (rowb + j) * 8] = ll_;
                    }
                }
            }
            BAR();
        }
    } else if (wv == 6) {
        // =================== layer2 role (wave 6) ===================
        s8v Bh[4][2], Bl[4][2];
        float bias[4];
#pragma unroll
        for (int g = 0; g < 4; ++g) {
            int n = g * 16 + fc;
            bias[g] = b2[n];
#pragma unroll
            for (int kc = 0; kc < 2; ++kc)
                load_bfrag(W2, U2, 32, 48, 64, kc * 32 + fr * 8, n, Bh[g][kc], Bl[g][kc]);
        }
#pragma unroll
        for (int g = 0; g < 4; ++g) {
            PIN(bias[g]);
#pragma unroll
            for (int kc = 0; kc < 2; ++kc) { PIN(Bh[g][kc]); PIN(Bl[g][kc]); }
        }
        float c2[2] = {0.f, 0.f};
        const int ibw = (fc >> 3) * 128 + (fc & 7);     // k = fc (0..15)
        __syncthreads();                                // barrier #2
        for (int s = 0; s < T_STEPS + 2; ++s) {
            if (s >= 2) {
                const int p = s & 1;
                const ushort_t* r1 = rb + (p << 9);     // H1,H2 parity stride 512
                s8v ah[2], al[2];
                ah[0] = *(const s8v*)&r1[H1H];
                al[0] = *(const s8v*)&r1[H1L];
                ah[1] = *(const s8v*)&r1[H2H];
                al[1] = *(const s8v*)&r1[H2L];
                f4v acc[4];
#pragma unroll
                for (int g = 0; g < 4; ++g) acc[g] = (f4v){bias[g], bias[g], bias[g], bias[g]};
#pragma unroll
                for (int kc = 0; kc < 2; ++kc) {
#pragma unroll
                    for (int g = 0; g < 4; ++g)
                        acc[g] = __builtin_amdgcn_mfma_f32_16x16x32_bf16(ah[kc], Bh[g][kc], acc[g], 0, 0, 0);
#pragma unroll
                    for (int g = 0; g < 4; ++g)
                        acc[g] = __builtin_amdgcn_mfma_f32_16x16x32_bf16(al[kc], Bh[g][kc], acc[g], 0, 0, 0);
#pragma unroll
                    for (int g = 0; g < 4; ++g)
                        acc[g] = __builtin_amdgcn_mfma_f32_16x16x32_bf16(ah[kc], Bl[g][kc], acc[g], 0, 0, 0);
                }
                float hn[2];
                gates2(acc, low, c2, hn);
                {
                    ushort_t* w = SMEM + ((p ^ 1) << 9) + ibw;
#pragma unroll
                    for (int j = 0; j < 2; ++j) {
                        unsigned short hh_, ll_;
                        tsplit(hn[j], hh_, ll_);
                        w[H2H + (rowb + j) * 8] = hh_;
                        w[H2L + (rowb + j) * 8] = ll_;
                    }
                    if (s == T_STEPS + 1) {             // t2 = 255: final h2
#pragma unroll
                        for (int j = 0; j < 2; ++j) h2last[rowb + j][fc] = hn[j];
                    }
                }
            }
            BAR();
        }
    } else {
        // =================== z_x producer role (wave 7) ===================
        // chunk c covers t = 2c, 2c+1 (128 chunks). During steps {2c, 2c+1}
        // produce chunk c+1 into parity (c+1)&1; consumers read chunk c.
        float bw[16];
#pragma unroll
        for (int cg = 0; cg < 16; ++cg) bw[cg] = b0[cg * 16 + fc];
        const int tl = fc >> 3;                         // A-row t_local
        const float* xlane = x + ((size_t)(bbase + (fc & 7)) * T_STEPS) * 64 + fr * 8;

        auto xload = [&](int cc, float4* rx) {
            const float* p = xlane + (size_t)(cc * 2 + tl) * 64;
            rx[0] = *(const float4*)(p);
            rx[1] = *(const float4*)(p + 4);
            rx[2] = *(const float4*)(p + 32);
            rx[3] = *(const float4*)(p + 36);
        };
        auto dotsplit = [&](const float4* rx, s8v* axh, s8v* axl) {
#pragma unroll
            for (int kc = 0; kc < 2; ++kc) {
                float vv[8] = {rx[kc*2].x, rx[kc*2].y, rx[kc*2].z, rx[kc*2].w,
                               rx[kc*2+1].x, rx[kc*2+1].y, rx[kc*2+1].z, rx[kc*2+1].w};
#pragma unroll
                for (int j = 0; j < 8; ++j) {
                    unsigned short h_, l_;
                    tsplit(vv[j], h_, l_);
                    axh[kc][j] = (short)h_;
                    axl[kc][j] = (short)l_;
                }
            }
        };

        s8v axh[2], axl[2];
        float4 rxA[4], rxB[4], rt[4];
        // prologue: produce chunk 0 (parity 0); prep frags for chunk 1;
        // prefetch raw x of chunk 2 into rxA. (W0S ready after barrier #1.)
        xload(0, rt);
        dotsplit(rt, axh, axl);
        produce8p<0>(axh, axl, bw, 0, lane, fr, fc, W0S, ZX);
        produce8p<8>(axh, axl, bw, 0, lane, fr, fc, W0S, ZX);
        xload(1, rt);
        dotsplit(rt, axh, axl);
        xload(2, rxA);
        __syncthreads();                                // barrier #2
        for (int s = 0; s < T_STEPS + 2; ++s) {
            if (s < 2 * 127) {                          // last produced chunk = 127
                const int c = s >> 1;
                const int pcpar = (c + 1) & 1;
                if ((s & 1) == 0) {
                    produce8p<0>(axh, axl, bw, pcpar, lane, fr, fc, W0S, ZX);
                } else {
                    produce8p<8>(axh, axl, bw, pcpar, lane, fr, fc, W0S, ZX);
                    // frags for chunk c+2 (raw loaded 2 steps ago); then issue
                    // raw loads for chunk c+3 into the other buffer.
                    if (c + 2 <= 127) {
                        if ((c & 1) == 0) dotsplit(rxA, axh, axl);
                        else              dotsplit(rxB, axh, axl);
                    }
                    if (c + 3 <= 127) {
                        if ((c & 1) == 0) xload(c + 3, rxB);
                        else              xload(c + 3, rxA);
                    }
                }
            }
            BAR();
        }
    }

    __syncthreads();
    // =================== dense head ===================
    if (tid < BT) {
        float acc = bd[0];
#pragma unroll
        for (int j = 0; j < 16; ++j) acc += h2last[tid][j] * Wd[j];
        out[bbase + tid] = acc;
    }
}

extern "C" void kernel_launch(void* const* d_in, const int* in_sizes, int n_in,
                              void* d_out, int out_size, void* d_ws, size_t ws_size,
                              hipStream_t stream) {
    (void)in_sizes; (void)n_in; (void)d_ws; (void)ws_size; (void)out_size;
    const float* x  = (const float*)d_in[0];
    const float* W0 = (const float*)d_in[1];
    const float* U0 = (const float*)d_in[2];
    const float* b0 = (const float*)d_in[3];
    const float* W1 = (const float*)d_in[4];
    const float* U1 = (const float*)d_in[5];
    const float* b1 = (const float*)d_in[6];
    const float* W2 = (const float*)d_in[7];
    const float* U2 = (const float*)d_in[8];
    const float* b2 = (const float*)d_in[9];
    const float* Wd = (const float*)d_in[10];
    const float* bd = (const float*)d_in[11];
    float* out = (float*)d_out;

    dim3 grid(2048 / BT);   // 256 blocks, 1 per CU
    dim3 block(512);        // 8 waves, 2 per SIMD
    hipLaunchKernelGGL(lstm_pipe, grid, block, 0, stream,
                       x, W0, U0, b0, W1, U1, b1, W2, U2, b2, Wd, bd, out);
}

// Round 7
// 452.121 us; speedup vs baseline: 1.2380x; 1.1980x over previous
//
#include <hip/hip_runtime.h>

// Fused 3-layer LSTM + dense head, layer-pipelined wave specialization.
// B=2048, T=256, F=64, H=[64,32,16], OUT=1. fp32 in/out.
//
// bf16 3-term split MFMA (ah*wh + al*wh + ah*wl) for ~2^-16 precision.
// Block = 512 threads = 8 waves, grid = 256 (1 block/CU, BT=8 batches).
//   waves 0-3 : layer0 at step t    waves 4-5 : layer1 at t-1
//   wave  6   : layer2 at t-2       wave  7   : x-stager (t+1, 2-deep pipeline)
//
// Round-13: REVERT to the verified R1 structure (302us counters). The z_x
// producer experiments (R3/R6) lost >40%: hipcc re-serialized the producer's
// ds_read->MFMA inner loop to minimize VGPRs (R6 VGPR=96 proves frags were
// not kept resident), leaving ~1800cy/step exposed LDS latency on wave 7.
// On top of R1, two critical-path cuts:
//  * split-accumulator MFMA chains: L0 = two independent chains (X-half
//    kc{0,1}+bias, H-half kc{2,3}+0) interleaved group-wise -> same-acc
//    distance 8, MFMA latency fully pipelined (was one distance-4 chain,
//    ~100cy/step exposed). L1: 3 chains (per kc). L2: 2 chains.
//  * s_setprio(1) around the dependent MFMA+gates section (0 before the
//    h-write; stager stays 0): SIMDs host role-split pairs (L0+L1 etc),
//    so priority favors whichever wave is inside its serial chain.

typedef __attribute__((ext_vector_type(8))) short s8v;   // 8 x bf16
typedef __attribute__((ext_vector_type(4))) float f4v;   // 4 x f32
typedef unsigned short ushort_t;

#define T_STEPS 256
#define BT 8

// SMEM layout (units: shorts). chunk = [kgrp 0..3][row 0..15][j 0..7] = 512 shorts.
#define XH  0       // [par][2 chunks], parity stride 1024
#define XL  2048
#define H0H 4096    // [par][2 chunks], parity stride 1024
#define H0L 6144
#define H1H 8192    // [par][1 chunk],  parity stride 512
#define H1L 9216
#define H2H 10240   // [par][1 chunk],  parity stride 512 (k 16..31 = zero pad)
#define H2L 11264
#define SM_SHORTS 12288

#define PIN(v) asm volatile("" : "+v"(v))
#define BAR()  asm volatile("s_waitcnt lgkmcnt(0)\n\ts_barrier" ::: "memory")

__device__ __forceinline__ unsigned short f2bf(float f) {      // RTNE (weights, one-time)
    unsigned u = __float_as_uint(f);
    u += 0x7fff + ((u >> 16) & 1);
    return (unsigned short)(u >> 16);
}
__device__ __forceinline__ float bf2f(unsigned short s) {
    return __uint_as_float(((unsigned)s) << 16);
}
// cheap truncation split: hi = top 16 bits, lo = trunc(v - hi). Error <= 2^-16*|v|.
__device__ __forceinline__ void tsplit(float v, unsigned short& hi, unsigned short& lo) {
    unsigned u = __float_as_uint(v);
    hi = (unsigned short)(u >> 16);
    float r = v - __uint_as_float(u & 0xffff0000u);   // exact
    lo = (unsigned short)(__float_as_uint(r) >> 16);
}
__device__ __forceinline__ float sigmoid_f(float x) {
    return __builtin_amdgcn_rcpf(1.0f + __expf(-x));
}
__device__ __forceinline__ float tanh_f(float x) {
    return 1.0f - 2.0f * __builtin_amdgcn_rcpf(__expf(2.0f * x) + 1.0f);
}

// combined [W;U] weight element, zero-padded past KH rows
__device__ __forceinline__ float wval(const float* W, const float* U,
                                      int inDim, int KH, int fourH, int k, int n) {
    if (k < inDim) return W[k * fourH + n];
    if (k < KH)    return U[(k - inDim) * fourH + n];
    return 0.0f;
}
__device__ __forceinline__ void load_bfrag(const float* W, const float* U,
                                           int inDim, int KH, int fourH,
                                           int k0, int n, s8v& hi, s8v& lo) {
#pragma unroll
    for (int j = 0; j < 8; ++j) {
        float w = wval(W, U, inDim, KH, fourH, k0 + j, n);
        unsigned short h = f2bf(w);
        unsigned short l = f2bf(w - bf2f(h));
        hi[j] = (short)h;
        lo[j] = (short)l;
    }
}

// Gate math on 2 rows/lane after full-wave redistribution:
//   low lanes (fr<2)  : own regs {0,1}       -> rows fr*4 + {0,1}
//   high lanes (fr>=2): partner regs {2,3}   -> rows (fr-2)*4 + {2,3}
__device__ __forceinline__ void gates2(const f4v* acc, bool low, float* c, float* hn) {
#pragma unroll
    for (int j = 0; j < 2; ++j) {
        float si = __shfl_xor(acc[0][j + 2], 32);
        float sf = __shfl_xor(acc[1][j + 2], 32);
        float sg = __shfl_xor(acc[2][j + 2], 32);
        float so = __shfl_xor(acc[3][j + 2], 32);
        float zi = low ? acc[0][j] : si;
        float zf = low ? acc[1][j] : sf;
        float zg = low ? acc[2][j] : sg;
        float zo = low ? acc[3][j] : so;
        float ig = sigmoid_f(zi);
        float fg = sigmoid_f(zf);
        float gg = tanh_f(zg);
        float og = sigmoid_f(zo);
        c[j] = fmaf(fg, c[j], ig * gg);
        hn[j] = og * tanh_f(c[j]);
    }
}

__global__ __attribute__((amdgpu_flat_work_group_size(512, 512),
                          amdgpu_waves_per_eu(2, 2)))
void lstm_pipe(const float* __restrict__ x,
               const float* __restrict__ W0, const float* __restrict__ U0, const float* __restrict__ b0,
               const float* __restrict__ W1, const float* __restrict__ U1, const float* __restrict__ b1,
               const float* __restrict__ W2, const float* __restrict__ U2, const float* __restrict__ b2,
               const float* __restrict__ Wd, const float* __restrict__ bd,
               float* __restrict__ out)
{
    const int tid  = threadIdx.x;
    const int lane = tid & 63;
    const int wv   = tid >> 6;          // 0..7
    const int fr   = lane >> 4;         // k-group / C row-group
    const int fc   = lane & 15;         // frag column
    const int bbase = blockIdx.x * BT;

    __shared__ __align__(16) ushort_t SMEM[SM_SHORTS];
    __shared__ __align__(16) float h2last[BT][16];

    // zero all staging (rows 8..15 of every chunk must stay zero; h init = 0)
    {
        unsigned* p32 = (unsigned*)SMEM;
        for (int i = tid; i < SM_SHORTS / 2; i += 512) p32[i] = 0u;
    }
    __syncthreads();                                    // barrier #1

    const ushort_t* rb = SMEM + lane * 8;               // frag read base (all roles)
    const bool low = (lane < 32);
    const int rowb = (fr & 1) * 4 + ((fr >> 1) << 1);   // this lane's h row base (0,4,2,6)

    if (wv < 4) {
        // =================== layer0 role (waves 0..3) ===================
        s8v Bh[4][4], Bl[4][4];                         // [gate][kc]
        float bias[4];
#pragma unroll
        for (int g = 0; g < 4; ++g) {
            int n = g * 64 + wv * 16 + fc;
            bias[g] = b0[n];
#pragma unroll
            for (int kc = 0; kc < 4; ++kc)
                load_bfrag(W0, U0, 64, 128, 256, kc * 32 + fr * 8, n, Bh[g][kc], Bl[g][kc]);
        }
#pragma unroll
        for (int g = 0; g < 4; ++g) {
            PIN(bias[g]);
#pragma unroll
            for (int kc = 0; kc < 4; ++kc) { PIN(Bh[g][kc]); PIN(Bl[g][kc]); }
        }
        float c0[2] = {0.f, 0.f};
        const int hq  = wv >> 1;                        // h0 chunk this wave writes
        const int k   = (wv & 1) * 16 + fc;             // k within chunk
        const int ibw = (k >> 3) * 128 + (k & 7);       // lane-dep write offset
        __syncthreads();                                // barrier #2
        for (int s = 0; s < T_STEPS + 2; ++s) {
            if (s < T_STEPS) {
                const ushort_t* r = rb + ((s & 1) << 10);   // parity*1024 shorts
                s8v ah[4], al[4];
                ah[0] = *(const s8v*)&r[XH  +   0];
                al[0] = *(const s8v*)&r[XL  +   0];
                ah[1] = *(const s8v*)&r[XH  + 512];
                al[1] = *(const s8v*)&r[XL  + 512];
                ah[2] = *(const s8v*)&r[H0H +   0];
                al[2] = *(const s8v*)&r[H0L +   0];
                ah[3] = *(const s8v*)&r[H0H + 512];
                al[3] = *(const s8v*)&r[H0L + 512];
                __builtin_amdgcn_s_setprio(1);
                // two independent chains: A = X half (kc 0,1) + bias, B = H half (kc 2,3).
                // group-interleaved -> same-acc distance 8, latency fully pipelined.
                f4v accA[4], accB[4];
#pragma unroll
                for (int g = 0; g < 4; ++g) {
                    accA[g] = (f4v){bias[g], bias[g], bias[g], bias[g]};
                    accB[g] = (f4v){0.f, 0.f, 0.f, 0.f};
                }
#pragma unroll
                for (int kc = 0; kc < 2; ++kc) {
#pragma unroll
                    for (int g = 0; g < 4; ++g)
                        accA[g] = __builtin_amdgcn_mfma_f32_16x16x32_bf16(ah[kc], Bh[g][kc], accA[g], 0, 0, 0);
#pragma unroll
                    for (int g = 0; g < 4; ++g)
                        accB[g] = __builtin_amdgcn_mfma_f32_16x16x32_bf16(ah[kc + 2], Bh[g][kc + 2], accB[g], 0, 0, 0);
#pragma unroll
                    for (int g = 0; g < 4; ++g)
                        accA[g] = __builtin_amdgcn_mfma_f32_16x16x32_bf16(al[kc], Bh[g][kc], accA[g], 0, 0, 0);
#pragma unroll
                    for (int g = 0; g < 4; ++g)
                        accB[g] = __builtin_amdgcn_mfma_f32_16x16x32_bf16(al[kc + 2], Bh[g][kc + 2], accB[g], 0, 0, 0);
#pragma unroll
                    for (int g = 0; g < 4; ++g)
                        accA[g] = __builtin_amdgcn_mfma_f32_16x16x32_bf16(ah[kc], Bl[g][kc], accA[g], 0, 0, 0);
#pragma unroll
                    for (int g = 0; g < 4; ++g)
                        accB[g] = __builtin_amdgcn_mfma_f32_16x16x32_bf16(ah[kc + 2], Bl[g][kc + 2], accB[g], 0, 0, 0);
                }
                f4v acc[4];
#pragma unroll
                for (int g = 0; g < 4; ++g) acc[g] = accA[g] + accB[g];
                float hn[2];
                gates2(acc, low, c0, hn);
                __builtin_amdgcn_s_setprio(0);
                {
                    ushort_t* w = SMEM + (((s & 1) ^ 1) << 10) + hq * 512 + ibw;
#pragma unroll
                    for (int j = 0; j < 2; ++j) {
                        unsigned short hh_, ll_;
                        tsplit(hn[j], hh_, ll_);
                        w[H0H + (rowb + j) * 8] = hh_;
                        w[H0L + (rowb + j) * 8] = ll_;
                    }
                }
            }
            BAR();
        }
    } else if (wv < 6) {
        // =================== layer1 role (waves 4,5) ===================
        s8v Bh[4][3], Bl[4][3];
        float bias[4];
#pragma unroll
        for (int g = 0; g < 4; ++g) {
            int n = g * 32 + (wv & 1) * 16 + fc;
            bias[g] = b1[n];
#pragma unroll
            for (int kc = 0; kc < 3; ++kc)
                load_bfrag(W1, U1, 64, 96, 128, kc * 32 + fr * 8, n, Bh[g][kc], Bl[g][kc]);
        }
#pragma unroll
        for (int g = 0; g < 4; ++g) {
            PIN(bias[g]);
#pragma unroll
            for (int kc = 0; kc < 3; ++kc) { PIN(Bh[g][kc]); PIN(Bl[g][kc]); }
        }
        float c1[2] = {0.f, 0.f};
        const int k   = (wv & 1) * 16 + fc;
        const int ibw = (k >> 3) * 128 + (k & 7);
        __syncthreads();                                // barrier #2
        for (int s = 0; s < T_STEPS + 2; ++s) {
            if (s >= 1 && s <= T_STEPS) {
                const int p = s & 1;
                const ushort_t* r  = rb + (p << 10);    // H0 parity stride 1024
                const ushort_t* r1 = rb + (p << 9);     // H1 parity stride 512
                s8v ah[3], al[3];
                ah[0] = *(const s8v*)&r[H0H +   0];
                al[0] = *(const s8v*)&r[H0L +   0];
                ah[1] = *(const s8v*)&r[H0H + 512];
                al[1] = *(const s8v*)&r[H0L + 512];
                ah[2] = *(const s8v*)&r1[H1H];
                al[2] = *(const s8v*)&r1[H1L];
                __builtin_amdgcn_s_setprio(1);
                // three independent chains, one per kc; distance 12.
                f4v accA[4], accB[4], accC[4];
#pragma unroll
                for (int g = 0; g < 4; ++g) {
                    accA[g] = (f4v){bias[g], bias[g], bias[g], bias[g]};
                    accB[g] = (f4v){0.f, 0.f, 0.f, 0.f};
                    accC[g] = (f4v){0.f, 0.f, 0.f, 0.f};
                }
#pragma unroll
                for (int g = 0; g < 4; ++g)
                    accA[g] = __builtin_amdgcn_mfma_f32_16x16x32_bf16(ah[0], Bh[g][0], accA[g], 0, 0, 0);
#pragma unroll
                for (int g = 0; g < 4; ++g)
                    accB[g] = __builtin_amdgcn_mfma_f32_16x16x32_bf16(ah[1], Bh[g][1], accB[g], 0, 0, 0);
#pragma unroll
                for (int g = 0; g < 4; ++g)
                    accC[g] = __builtin_amdgcn_mfma_f32_16x16x32_bf16(ah[2], Bh[g][2], accC[g], 0, 0, 0);
#pragma unroll
                for (int g = 0; g < 4; ++g)
                    accA[g] = __builtin_amdgcn_mfma_f32_16x16x32_bf16(al[0], Bh[g][0], accA[g], 0, 0, 0);
#pragma unroll
                for (int g = 0; g < 4; ++g)
                    accB[g] = __builtin_amdgcn_mfma_f32_16x16x32_bf16(al[1], Bh[g][1], accB[g], 0, 0, 0);
#pragma unroll
                for (int g = 0; g < 4; ++g)
                    accC[g] = __builtin_amdgcn_mfma_f32_16x16x32_bf16(al[2], Bh[g][2], accC[g], 0, 0, 0);
#pragma unroll
                for (int g = 0; g < 4; ++g)
                    accA[g] = __builtin_amdgcn_mfma_f32_16x16x32_bf16(ah[0], Bl[g][0], accA[g], 0, 0, 0);
#pragma unroll
                for (int g = 0; g < 4; ++g)
                    accB[g] = __builtin_amdgcn_mfma_f32_16x16x32_bf16(ah[1], Bl[g][1], accB[g], 0, 0, 0);
#pragma unroll
                for (int g = 0; g < 4; ++g)
                    accC[g] = __builtin_amdgcn_mfma_f32_16x16x32_bf16(ah[2], Bl[g][2], accC[g], 0, 0, 0);
                f4v acc[4];
#pragma unroll
                for (int g = 0; g < 4; ++g) acc[g] = (accA[g] + accB[g]) + accC[g];
                float hn[2];
                gates2(acc, low, c1, hn);
                __builtin_amdgcn_s_setprio(0);
                {
                    ushort_t* w = SMEM + ((p ^ 1) << 9) + ibw;
#pragma unroll
                    for (int j = 0; j < 2; ++j) {
                        unsigned short hh_, ll_;
                        tsplit(hn[j], hh_, ll_);
                        w[H1H + (rowb + j) * 8] = hh_;
                        w[H1L + (rowb + j) * 8] = ll_;
                    }
                }
            }
            BAR();
        }
    } else if (wv == 6) {
        // =================== layer2 role (wave 6) ===================
        s8v Bh[4][2], Bl[4][2];
        float bias[4];
#pragma unroll
        for (int g = 0; g < 4; ++g) {
            int n = g * 16 + fc;
            bias[g] = b2[n];
#pragma unroll
            for (int kc = 0; kc < 2; ++kc)
                load_bfrag(W2, U2, 32, 48, 64, kc * 32 + fr * 8, n, Bh[g][kc], Bl[g][kc]);
        }
#pragma unroll
        for (int g = 0; g < 4; ++g) {
            PIN(bias[g]);
#pragma unroll
            for (int kc = 0; kc < 2; ++kc) { PIN(Bh[g][kc]); PIN(Bl[g][kc]); }
        }
        float c2[2] = {0.f, 0.f};
        const int ibw = (fc >> 3) * 128 + (fc & 7);     // k = fc (0..15)
        __syncthreads();                                // barrier #2
        for (int s = 0; s < T_STEPS + 2; ++s) {
            if (s >= 2) {
                const int p = s & 1;
                const ushort_t* r1 = rb + (p << 9);     // H1,H2 parity stride 512
                s8v ah[2], al[2];
                ah[0] = *(const s8v*)&r1[H1H];
                al[0] = *(const s8v*)&r1[H1L];
                ah[1] = *(const s8v*)&r1[H2H];
                al[1] = *(const s8v*)&r1[H2L];
                __builtin_amdgcn_s_setprio(1);
                // two independent chains, one per kc; distance 8.
                f4v accA[4], accB[4];
#pragma unroll
                for (int g = 0; g < 4; ++g) {
                    accA[g] = (f4v){bias[g], bias[g], bias[g], bias[g]};
                    accB[g] = (f4v){0.f, 0.f, 0.f, 0.f};
                }
#pragma unroll
                for (int g = 0; g < 4; ++g)
                    accA[g] = __builtin_amdgcn_mfma_f32_16x16x32_bf16(ah[0], Bh[g][0], accA[g], 0, 0, 0);
#pragma unroll
                for (int g = 0; g < 4; ++g)
                    accB[g] = __builtin_amdgcn_mfma_f32_16x16x32_bf16(ah[1], Bh[g][1], accB[g], 0, 0, 0);
#pragma unroll
                for (int g = 0; g < 4; ++g)
                    accA[g] = __builtin_amdgcn_mfma_f32_16x16x32_bf16(al[0], Bh[g][0], accA[g], 0, 0, 0);
#pragma unroll
                for (int g = 0; g < 4; ++g)
                    accB[g] = __builtin_amdgcn_mfma_f32_16x16x32_bf16(al[1], Bh[g][1], accB[g], 0, 0, 0);
#pragma unroll
                for (int g = 0; g < 4; ++g)
                    accA[g] = __builtin_amdgcn_mfma_f32_16x16x32_bf16(ah[0], Bl[g][0], accA[g], 0, 0, 0);
#pragma unroll
                for (int g = 0; g < 4; ++g)
                    accB[g] = __builtin_amdgcn_mfma_f32_16x16x32_bf16(ah[1], Bl[g][1], accB[g], 0, 0, 0);
                f4v acc[4];
#pragma unroll
                for (int g = 0; g < 4; ++g) acc[g] = accA[g] + accB[g];
                float hn[2];
                gates2(acc, low, c2, hn);
                __builtin_amdgcn_s_setprio(0);
                {
                    ushort_t* w = SMEM + ((p ^ 1) << 9) + ibw;
#pragma unroll
                    for (int j = 0; j < 2; ++j) {
                        unsigned short hh_, ll_;
                        tsplit(hn[j], hh_, ll_);
                        w[H2H + (rowb + j) * 8] = hh_;
                        w[H2L + (rowb + j) * 8] = ll_;
                    }
                    if (s == T_STEPS + 1) {             // t2 = 255: final h2
#pragma unroll
                        for (int j = 0; j < 2; ++j) h2last[rowb + j][fc] = hn[j];
                    }
                }
            }
            BAR();
        }
    } else {
        // =================== x-stager role (wave 7), 2-deep pipeline ===================
        const int xb = lane >> 3;                       // batch row 0..7
        const int fo = (lane & 7) * 8;                  // feature octet base
        const float* xp = x + ((size_t)(bbase + xb) * T_STEPS) * 64 + fo;
        const int o2 = (fo >> 5) * 512 + (((fo & 31) >> 3) * 16 + xb) * 8;

        auto write_x = [&](float4 v0, float4 v1, int tt) {
            float vv[8] = {v0.x, v0.y, v0.z, v0.w, v1.x, v1.y, v1.z, v1.w};
            s8v hi8, lo8;
#pragma unroll
            for (int j = 0; j < 8; ++j) {
                unsigned short h_, l_;
                tsplit(vv[j], h_, l_);
                hi8[j] = (short)h_;
                lo8[j] = (short)l_;
            }
            ushort_t* wbp = SMEM + ((tt & 1) << 10) + o2;
            *(s8v*)&wbp[XH] = hi8;
            *(s8v*)&wbp[XL] = lo8;
        };

        // prologue: write x(0), prefetch x(1) into regs
        float4 pa = *(const float4*)(xp);
        float4 pb = *(const float4*)(xp + 4);
        write_x(pa, pb, 0);
        pa = *(const float4*)(xp + 64);
        pb = *(const float4*)(xp + 64 + 4);
        __syncthreads();                                // barrier #2
        for (int s = 0; s < T_STEPS + 2; ++s) {
            float4 na, nb;
            const bool ld = (s + 2 < T_STEPS);
            if (ld) {                                   // issue x(s+2) early
                na = *(const float4*)(xp + (size_t)(s + 2) * 64);
                nb = *(const float4*)(xp + (size_t)(s + 2) * 64 + 4);
            }
            if (s + 1 < T_STEPS) write_x(pa, pb, s + 1);   // waits on load from s-1
            if (ld) { pa = na; pb = nb; }
            BAR();
        }
    }

    __syncthreads();
    // =================== dense head ===================
    if (tid < BT) {
        float acc = bd[0];
#pragma unroll
        for (int j = 0; j < 16; ++j) acc += h2last[tid][j] * Wd[j];
        out[bbase + tid] = acc;
    }
}

extern "C" void kernel_launch(void* const* d_in, const int* in_sizes, int n_in,
                              void* d_out, int out_size, void* d_ws, size_t ws_size,
                              hipStream_t stream) {
    (void)in_sizes; (void)n_in; (void)d_ws; (void)ws_size; (void)out_size;
    const float* x  = (const float*)d_in[0];
    const float* W0 = (const float*)d_in[1];
    const float* U0 = (const float*)d_in[2];
    const float* b0 = (const float*)d_in[3];
    const float* W1 = (const float*)d_in[4];
    const float* U1 = (const float*)d_in[5];
    const float* b1 = (const float*)d_in[6];
    const float* W2 = (const float*)d_in[7];
    const float* U2 = (const float*)d_in[8];
    const float* b2 = (const float*)d_in[9];
    const float* Wd = (const float*)d_in[10];
    const float* bd = (const float*)d_in[11];
    float* out = (float*)d_out;

    dim3 grid(2048 / BT);   // 256 blocks, 1 per CU
    dim3 block(512);        // 8 waves, 2 per SIMD
    hipLaunchKernelGGL(lstm_pipe, grid, block, 0, stream,
                       x, W0, U0, b0, W1, U1, b1, W2, U2, b2, Wd, bd, out);
}